// Round 2
// baseline (10632.640 us; speedup 1.0000x reference)
//
#include <hip/hip_runtime.h>
#include <hip/hip_bf16.h>
#include <math.h>

typedef short bf16x8 __attribute__((ext_vector_type(8)));
typedef float f32x4 __attribute__((ext_vector_type(4)));
typedef unsigned short u16;

#define NT 64
#define NB 512
#define NS 256
#define NA 64
#define NBEL 1024

// d_out element offsets (f32 elements)
#define OUT_B      0
#define OUT_SPRI   33554432
#define OUT_MUPRI  41943040
#define OUT_STDPRI 50331648
#define OUT_SPOS   58720256
#define OUT_MUPOS  67108864
#define OUT_STDPOS 75497472

__device__ __forceinline__ f32x4 mfma16(bf16x8 a, bf16x8 b, f32x4 c) {
  return __builtin_amdgcn_mfma_f32_16x16x32_bf16(a, b, c, 0, 0, 0);
}

__device__ __forceinline__ u16 f2bf(float f) {
  union { float f; unsigned u; } v; v.f = f;
  return (u16)((v.u + 0x7FFFu + ((v.u >> 16) & 1u)) >> 16);
}

__device__ __forceinline__ bf16x8 ld8bf(const u16* p) { return *(const bf16x8*)p; }

__device__ __forceinline__ bf16x8 cvt8(const float* p) {
  const float4 lo = *(const float4*)p;
  const float4 hi = *(const float4*)(p + 4);
  bf16x8 v;
  v[0] = (short)f2bf(lo.x); v[1] = (short)f2bf(lo.y);
  v[2] = (short)f2bf(lo.z); v[3] = (short)f2bf(lo.w);
  v[4] = (short)f2bf(hi.x); v[5] = (short)f2bf(hi.y);
  v[6] = (short)f2bf(hi.z); v[7] = (short)f2bf(hi.w);
  return v;
}

__device__ __forceinline__ float sigm(float x) { return 1.f / (1.f + __expf(-x)); }
__device__ __forceinline__ float softplus_(float x) {
  if (x > 20.f) return x;
  return log1pf(__expf(x));
}

#define ZACC(acc) { acc[0][0] = (f32x4){0.f,0.f,0.f,0.f}; acc[0][1] = (f32x4){0.f,0.f,0.f,0.f}; \
                    acc[1][0] = (f32x4){0.f,0.f,0.f,0.f}; acc[1][1] = (f32x4){0.f,0.f,0.f,0.f}; }

#define Q4(acc, a0v, a1v, b0v, b1v) \
  acc[0][0] = mfma16(a0v, b0v, acc[0][0]); \
  acc[0][1] = mfma16(a0v, b1v, acc[0][1]); \
  acc[1][0] = mfma16(a1v, b0v, acc[1][0]); \
  acc[1][1] = mfma16(a1v, b1v, acc[1][1]);

// -------- P0: weights f32 -> bf16 into ws (contiguous segments) --------
__global__ __launch_bounds__(256) void cvt_weights_k(
    const float* __restrict__ wsa, const float* __restrict__ wih,
    const float* __restrict__ whh, const float* __restrict__ wbpri,
    const float* __restrict__ wspri, const float* __restrict__ wbpos,
    const float* __restrict__ wspos, u16* __restrict__ dst) {
  const int S0 = 327680;
  const int S1 = S0 + 3145728;
  const int S2 = S1 + 3145728;
  const int S3 = S2 + 1048576;
  const int S4 = S3 + 524288;
  const int S5 = S4 + 2097152;
  const int S6 = S5 + 524288;  // 10,813,440
  for (int i = blockIdx.x * blockDim.x + threadIdx.x; i < S6;
       i += gridDim.x * blockDim.x) {
    float v;
    if (i < S0) v = wsa[i];
    else if (i < S1) v = wih[i - S0];
    else if (i < S2) v = whh[i - S1];
    else if (i < S3) v = wbpri[i - S2];
    else if (i < S4) v = wspri[i - S3];
    else if (i < S5) v = wbpos[i - S4];
    else v = wspos[i - S5];
    dst[i] = f2bf(v);
  }
}

// -------- P1: init carries --------
__global__ __launch_bounds__(256) void init_carry_k(
    const float* __restrict__ s0, const float* __restrict__ b0,
    const float* __restrict__ Mptr, u16* __restrict__ smask,
    u16* __restrict__ bbf, float* __restrict__ hf) {
  for (int i = blockIdx.x * blockDim.x + threadIdx.x; i < NB * NBEL;
       i += gridDim.x * blockDim.x) {
    float b = b0[i];
    bbf[i] = f2bf(b);
    hf[i] = b;
    if (i < NB * NS) {
      int row = i >> 8;
      smask[i] = f2bf(s0[i] * Mptr[row]);
    }
  }
}

// -------- K1: x = relu([s*m | a_t] @ Wsa^T + b_sa)  (blocks 0..127)
//         and gh = b @ Whh^T + b_hh                  (blocks 128..511)
__global__ __launch_bounds__(256) void k1_x_gh(
    const u16* __restrict__ smask, const float* __restrict__ Af,
    const u16* __restrict__ wsa, const float* __restrict__ b_sa,
    const u16* __restrict__ bbf, const u16* __restrict__ whh,
    const float* __restrict__ b_hh, u16* __restrict__ xbf,
    float* __restrict__ gh, int t) {
  const int l = threadIdx.x & 63, r16 = l & 15, kq = l >> 4;
  const int wid = threadIdx.x >> 6;
  const int bid = blockIdx.x;
  if (bid < 128) {
    const int bm = bid & 7, bn = bid >> 3;
    const int row0 = bm * 64 + (wid >> 1) * 32;
    const int col0 = bn * 64 + (wid & 1) * 32;
    f32x4 acc[2][2]; ZACC(acc);
    {
      const u16* A0 = smask + (row0 + r16) * NS + kq * 8;
      const u16* A1 = A0 + 16 * NS;
      const u16* B0 = wsa + (size_t)(col0 + r16) * 320 + kq * 8;
      const u16* B1 = B0 + 16 * 320;
#pragma unroll
      for (int k = 0; k < NS; k += 32) {
        bf16x8 a0 = ld8bf(A0 + k), a1 = ld8bf(A1 + k);
        bf16x8 b0 = ld8bf(B0 + k), b1 = ld8bf(B1 + k);
        Q4(acc, a0, a1, b0, b1);
      }
    }
    {
      const float* A0 = Af + (size_t)t * NB * NA + (row0 + r16) * NA + kq * 8;
      const float* A1 = A0 + 16 * NA;
      const u16* B0 = wsa + (size_t)(col0 + r16) * 320 + 256 + kq * 8;
      const u16* B1 = B0 + 16 * 320;
#pragma unroll
      for (int k = 0; k < NA; k += 32) {
        bf16x8 a0 = cvt8(A0 + k), a1 = cvt8(A1 + k);
        bf16x8 b0 = ld8bf(B0 + k), b1 = ld8bf(B1 + k);
        Q4(acc, a0, a1, b0, b1);
      }
    }
#pragma unroll
    for (int i = 0; i < 2; ++i)
#pragma unroll
      for (int j = 0; j < 2; ++j)
#pragma unroll
        for (int q = 0; q < 4; ++q) {
          const int row = row0 + i * 16 + kq * 4 + q;
          const int col = col0 + j * 16 + r16;
          const float v = acc[i][j][q] + b_sa[col];
          xbf[row * NBEL + col] = f2bf(fmaxf(v, 0.f));
        }
  } else {
    const int b2 = bid - 128;
    const int bm = b2 & 7, bn = b2 >> 3;  // bn in 0..47
    const int row0 = bm * 64 + (wid >> 1) * 32;
    const int col0 = bn * 64 + (wid & 1) * 32;
    f32x4 acc[2][2]; ZACC(acc);
    const u16* A0 = bbf + (row0 + r16) * NBEL + kq * 8;
    const u16* A1 = A0 + 16 * NBEL;
    const u16* B0 = whh + (size_t)(col0 + r16) * NBEL + kq * 8;
    const u16* B1 = B0 + 16 * NBEL;
    for (int k = 0; k < NBEL; k += 32) {
      bf16x8 a0 = ld8bf(A0 + k), a1 = ld8bf(A1 + k);
      bf16x8 b0 = ld8bf(B0 + k), b1 = ld8bf(B1 + k);
      Q4(acc, a0, a1, b0, b1);
    }
#pragma unroll
    for (int i = 0; i < 2; ++i)
#pragma unroll
      for (int j = 0; j < 2; ++j)
#pragma unroll
        for (int q = 0; q < 4; ++q) {
          const int row = row0 + i * 16 + kq * 4 + q;
          const int col = col0 + j * 16 + r16;
          gh[row * 3072 + col] = acc[i][j][q] + b_hh[col];
        }
  }
}

// -------- K2: gi = x @ Wih^T (3 chunks) fused with GRU gates -> b_new --------
__global__ __launch_bounds__(256) void k2_gi_gru(
    const u16* __restrict__ xbf, const u16* __restrict__ wih,
    const float* __restrict__ b_ih, const float* __restrict__ gh,
    float* __restrict__ hf, u16* __restrict__ bbf,
    float* __restrict__ out, int t) {
  const int l = threadIdx.x & 63, r16 = l & 15, kq = l >> 4;
  const int wid = threadIdx.x >> 6;
  const int bm = blockIdx.x & 7, bn = blockIdx.x >> 3;  // bn 0..15
  const int row0 = bm * 64 + (wid >> 1) * 32;
  const int col0 = bn * 64 + (wid & 1) * 32;
  f32x4 ar[2][2], az[2][2], an[2][2];
  ZACC(ar); ZACC(az); ZACC(an);
  const u16* A0 = xbf + (row0 + r16) * NBEL + kq * 8;
  const u16* A1 = A0 + 16 * NBEL;
  const u16* Br0 = wih + (size_t)(col0 + r16) * NBEL + kq * 8;
  const u16* Br1 = Br0 + 16 * NBEL;
  const u16* Bz0 = wih + (size_t)(col0 + 1024 + r16) * NBEL + kq * 8;
  const u16* Bz1 = Bz0 + 16 * NBEL;
  const u16* Bn0 = wih + (size_t)(col0 + 2048 + r16) * NBEL + kq * 8;
  const u16* Bn1 = Bn0 + 16 * NBEL;
  for (int k = 0; k < NBEL; k += 32) {
    bf16x8 a0 = ld8bf(A0 + k), a1 = ld8bf(A1 + k);
    bf16x8 b0 = ld8bf(Br0 + k), b1 = ld8bf(Br1 + k);
    Q4(ar, a0, a1, b0, b1);
    bf16x8 c0 = ld8bf(Bz0 + k), c1 = ld8bf(Bz1 + k);
    Q4(az, a0, a1, c0, c1);
    bf16x8 d0 = ld8bf(Bn0 + k), d1 = ld8bf(Bn1 + k);
    Q4(an, a0, a1, d0, d1);
  }
#pragma unroll
  for (int i = 0; i < 2; ++i)
#pragma unroll
    for (int j = 0; j < 2; ++j)
#pragma unroll
      for (int q = 0; q < 4; ++q) {
        const int row = row0 + i * 16 + kq * 4 + q;
        const int c = col0 + j * 16 + r16;
        const float gir = ar[i][j][q] + b_ih[c];
        const float giz = az[i][j][q] + b_ih[c + 1024];
        const float gin = an[i][j][q] + b_ih[c + 2048];
        const float* ghrow = gh + row * 3072;
        const float r = sigm(gir + ghrow[c]);
        const float z = sigm(giz + ghrow[c + 1024]);
        const float n = tanhf(gin + r * ghrow[c + 2048]);
        const float h = hf[row * NBEL + c];
        const float bnew = (1.f - z) * n + z * h;
        hf[row * NBEL + c] = bnew;
        bbf[row * NBEL + c] = f2bf(bnew);
        out[OUT_B + (size_t)t * (NB * NBEL) + row * NBEL + c] = bnew;
      }
}

// -------- K3: hb = relu([b_new | o_t] @ Wbpos^T + b_bpos) --------
__global__ __launch_bounds__(256) void k3_hb(
    const u16* __restrict__ bbf, const float* __restrict__ Of,
    const u16* __restrict__ wbpos, const float* __restrict__ b_bpos,
    u16* __restrict__ hbbf, int t) {
  const int l = threadIdx.x & 63, r16 = l & 15, kq = l >> 4;
  const int wid = threadIdx.x >> 6;
  const int bm = blockIdx.x & 7, bn = blockIdx.x >> 3;  // bn 0..15
  const int row0 = bm * 64 + (wid >> 1) * 32;
  const int col0 = bn * 64 + (wid & 1) * 32;
  f32x4 acc[2][2]; ZACC(acc);
  {
    const u16* A0 = bbf + (row0 + r16) * NBEL + kq * 8;
    const u16* A1 = A0 + 16 * NBEL;
    const u16* B0 = wbpos + (size_t)(col0 + r16) * 2048 + kq * 8;
    const u16* B1 = B0 + 16 * 2048;
    for (int k = 0; k < NBEL; k += 32) {
      bf16x8 a0 = ld8bf(A0 + k), a1 = ld8bf(A1 + k);
      bf16x8 b0 = ld8bf(B0 + k), b1 = ld8bf(B1 + k);
      Q4(acc, a0, a1, b0, b1);
    }
  }
  {
    const float* F0 = Of + (size_t)t * (NB * NBEL) + (row0 + r16) * NBEL + kq * 8;
    const float* F1 = F0 + 16 * NBEL;
    const u16* B0 = wbpos + (size_t)(col0 + r16) * 2048 + 1024 + kq * 8;
    const u16* B1 = B0 + 16 * 2048;
    for (int k = 0; k < NBEL; k += 32) {
      bf16x8 a0 = cvt8(F0 + k), a1 = cvt8(F1 + k);
      bf16x8 b0 = ld8bf(B0 + k), b1 = ld8bf(B1 + k);
      Q4(acc, a0, a1, b0, b1);
    }
  }
#pragma unroll
  for (int i = 0; i < 2; ++i)
#pragma unroll
    for (int j = 0; j < 2; ++j)
#pragma unroll
      for (int q = 0; q < 4; ++q) {
        const int row = row0 + i * 16 + kq * 4 + q;
        const int col = col0 + j * 16 + r16;
        const float v = acc[i][j][q] + b_bpos[col];
        hbbf[row * NBEL + col] = f2bf(fmaxf(v, 0.f));
      }
}

// -------- K4: pos = hb @ Wspos^T + b_spos; sample s_q; write carry --------
__global__ __launch_bounds__(256) void k4_spos(
    const u16* __restrict__ hbbf, const u16* __restrict__ wspos,
    const float* __restrict__ b_spos, const float* __restrict__ npos,
    const float* __restrict__ Mptr, float* __restrict__ out,
    u16* __restrict__ smask, int t) {
  const int l = threadIdx.x & 63, r16 = l & 15, kq = l >> 4;
  const int wid = threadIdx.x >> 6;
  const int bm = blockIdx.x & 7, bn = blockIdx.x >> 3;  // bn 0..3
  const int row0 = bm * 64 + (wid >> 1) * 32;
  const int c0 = bn * 64 + (wid & 1) * 32;  // mu column base in [0,256)
  f32x4 am[2][2], ah[2][2];
  ZACC(am); ZACC(ah);
  const u16* A0 = hbbf + (row0 + r16) * NBEL + kq * 8;
  const u16* A1 = A0 + 16 * NBEL;
  const u16* Bm0 = wspos + (size_t)(c0 + r16) * NBEL + kq * 8;
  const u16* Bm1 = Bm0 + 16 * NBEL;
  const u16* Bh0 = wspos + (size_t)(c0 + 256 + r16) * NBEL + kq * 8;
  const u16* Bh1 = Bh0 + 16 * NBEL;
  for (int k = 0; k < NBEL; k += 32) {
    bf16x8 a0 = ld8bf(A0 + k), a1 = ld8bf(A1 + k);
    bf16x8 m0 = ld8bf(Bm0 + k), m1 = ld8bf(Bm1 + k);
    Q4(am, a0, a1, m0, m1);
    bf16x8 h0 = ld8bf(Bh0 + k), h1 = ld8bf(Bh1 + k);
    Q4(ah, a0, a1, h0, h1);
  }
#pragma unroll
  for (int i = 0; i < 2; ++i)
#pragma unroll
    for (int j = 0; j < 2; ++j)
#pragma unroll
      for (int q = 0; q < 4; ++q) {
        const int row = row0 + i * 16 + kq * 4 + q;
        const int c = c0 + j * 16 + r16;
        const float mu = am[i][j][q] + b_spos[c];
        const float hq = ah[i][j][q] + b_spos[c + 256];
        const float sd = softplus_(hq) + 0.1f;
        const size_t idx = (size_t)t * (NB * NS) + row * NS + c;
        const float sq = mu + sd * npos[idx];
        out[OUT_SPOS + idx] = sq;
        out[OUT_MUPOS + idx] = mu;
        out[OUT_STDPOS + idx] = sd;
        const float mn = (t < NT - 1) ? Mptr[(t + 1) * NB + row] : 1.f;
        smask[row * NS + c] = f2bf(sq * mn);
      }
}

// -------- K5: deferred prior hidden, chunk of 8 steps (4096 rows) --------
__global__ __launch_bounds__(256) void k5_bpri(
    const float* __restrict__ ball, const u16* __restrict__ wbpri,
    const float* __restrict__ b_bpri, u16* __restrict__ hpri, int tc) {
  const int l = threadIdx.x & 63, r16 = l & 15, kq = l >> 4;
  const int wid = threadIdx.x >> 6;
  const int bm = blockIdx.x & 63, bn = blockIdx.x >> 6;  // bn 0..15
  const int row0 = bm * 64 + (wid >> 1) * 32;  // within 4096-row chunk
  const int col0 = bn * 64 + (wid & 1) * 32;
  f32x4 acc[2][2]; ZACC(acc);
  const float* Ab = ball + (size_t)tc * 4194304;
  const float* A0 = Ab + (size_t)(row0 + r16) * NBEL + kq * 8;
  const float* A1 = A0 + 16 * NBEL;
  const u16* B0 = wbpri + (size_t)(col0 + r16) * NBEL + kq * 8;
  const u16* B1 = B0 + 16 * NBEL;
  for (int k = 0; k < NBEL; k += 32) {
    bf16x8 a0 = cvt8(A0 + k), a1 = cvt8(A1 + k);
    bf16x8 b0 = ld8bf(B0 + k), b1 = ld8bf(B1 + k);
    Q4(acc, a0, a1, b0, b1);
  }
#pragma unroll
  for (int i = 0; i < 2; ++i)
#pragma unroll
    for (int j = 0; j < 2; ++j)
#pragma unroll
      for (int q = 0; q < 4; ++q) {
        const int row = row0 + i * 16 + kq * 4 + q;
        const int col = col0 + j * 16 + r16;
        const float v = acc[i][j][q] + b_bpri[col];
        hpri[(size_t)row * NBEL + col] = f2bf(fmaxf(v, 0.f));
      }
}

// -------- K6: deferred prior head + sample, chunk of 8 steps --------
__global__ __launch_bounds__(256) void k6_spri(
    const u16* __restrict__ hpri, const u16* __restrict__ wspri,
    const float* __restrict__ b_spri, const float* __restrict__ npri,
    float* __restrict__ out, int tc) {
  const int l = threadIdx.x & 63, r16 = l & 15, kq = l >> 4;
  const int wid = threadIdx.x >> 6;
  const int bm = blockIdx.x & 63, bn = blockIdx.x >> 6;  // bn 0..3
  const int row0 = bm * 64 + (wid >> 1) * 32;
  const int c0 = bn * 64 + (wid & 1) * 32;
  f32x4 am[2][2], ah[2][2];
  ZACC(am); ZACC(ah);
  const u16* A0 = hpri + (size_t)(row0 + r16) * NBEL + kq * 8;
  const u16* A1 = A0 + 16 * NBEL;
  const u16* Bm0 = wspri + (size_t)(c0 + r16) * NBEL + kq * 8;
  const u16* Bm1 = Bm0 + 16 * NBEL;
  const u16* Bh0 = wspri + (size_t)(c0 + 256 + r16) * NBEL + kq * 8;
  const u16* Bh1 = Bh0 + 16 * NBEL;
  for (int k = 0; k < NBEL; k += 32) {
    bf16x8 a0 = ld8bf(A0 + k), a1 = ld8bf(A1 + k);
    bf16x8 m0 = ld8bf(Bm0 + k), m1 = ld8bf(Bm1 + k);
    Q4(am, a0, a1, m0, m1);
    bf16x8 h0 = ld8bf(Bh0 + k), h1 = ld8bf(Bh1 + k);
    Q4(ah, a0, a1, h0, h1);
  }
#pragma unroll
  for (int i = 0; i < 2; ++i)
#pragma unroll
    for (int j = 0; j < 2; ++j)
#pragma unroll
      for (int q = 0; q < 4; ++q) {
        const int row = row0 + i * 16 + kq * 4 + q;
        const int c = c0 + j * 16 + r16;
        const size_t rowg = (size_t)tc * 4096 + row;
        const size_t idx = rowg * NS + c;
        const float mu = am[i][j][q] + b_spri[c];
        const float hp = ah[i][j][q] + b_spri[c + 256];
        const float sd = softplus_(hp) + 0.1f;
        out[OUT_SPRI + idx] = mu + sd * npri[idx];
        out[OUT_MUPRI + idx] = mu;
        out[OUT_STDPRI + idx] = sd;
      }
}

extern "C" void kernel_launch(void* const* d_in, const int* in_sizes, int n_in,
                              void* d_out, int out_size, void* d_ws, size_t ws_size,
                              hipStream_t stream) {
  const float* s0 = (const float*)d_in[0];
  const float* Af = (const float*)d_in[1];
  const float* b0 = (const float*)d_in[2];
  const float* Of = (const float*)d_in[3];
  const float* Mp = (const float*)d_in[4];
  const float* npri = (const float*)d_in[5];
  const float* npos = (const float*)d_in[6];
  const float* Wsa = (const float*)d_in[7];
  const float* bsa = (const float*)d_in[8];
  const float* Wih = (const float*)d_in[9];
  const float* bih = (const float*)d_in[10];
  const float* Whh = (const float*)d_in[11];
  const float* bhh = (const float*)d_in[12];
  const float* Wbpri = (const float*)d_in[13];
  const float* bbpri = (const float*)d_in[14];
  const float* Wspri = (const float*)d_in[15];
  const float* bspri = (const float*)d_in[16];
  const float* Wbpos = (const float*)d_in[17];
  const float* bbpos = (const float*)d_in[18];
  const float* Wspos = (const float*)d_in[19];
  const float* bspos = (const float*)d_in[20];

  float* out = (float*)d_out;
  char* ws = (char*)d_ws;
  u16* wbase   = (u16*)ws;                 // weight bf16 segments, contiguous
  u16* wsa_b   = wbase;
  u16* wih_b   = wbase + 327680;
  u16* whh_b   = wbase + 3473408;
  u16* wbpri_b = wbase + 6619136;
  u16* wspri_b = wbase + 7667712;
  u16* wbpos_b = wbase + 8192000;
  u16* wspos_b = wbase + 10289152;
  // weights end at byte 21,626,880
  u16*   smask = (u16*)  (ws + 21626880);  // [512,256] bf16
  u16*   bbf   = (u16*)  (ws + 21889024);  // [512,1024] bf16
  float* hf    = (float*)(ws + 22937600);  // [512,1024] f32
  u16*   xbf   = (u16*)  (ws + 25034752);  // [512,1024] bf16
  float* gh    = (float*)(ws + 26083328);  // [512,3072] f32
  u16*   hbbf  = (u16*)  (ws + 32374784);  // [512,1024] bf16
  u16*   hpri  = (u16*)  (ws + 33423360);  // [4096,1024] bf16 chunk (8 steps)
  // ws end: 41,811,968 bytes

  cvt_weights_k<<<2048, 256, 0, stream>>>(Wsa, Wih, Whh, Wbpri, Wspri, Wbpos,
                                          Wspos, wbase);
  init_carry_k<<<2048, 256, 0, stream>>>(s0, b0, Mp, smask, bbf, hf);

  for (int t = 0; t < NT; ++t) {
    k1_x_gh<<<512, 256, 0, stream>>>(smask, Af, wsa_b, bsa, bbf, whh_b, bhh,
                                     xbf, gh, t);
    k2_gi_gru<<<128, 256, 0, stream>>>(xbf, wih_b, bih, gh, hf, bbf, out, t);
    k3_hb<<<128, 256, 0, stream>>>(bbf, Of, wbpos_b, bbpos, hbbf, t);
    k4_spos<<<32, 256, 0, stream>>>(hbbf, wspos_b, bspos, npos, Mp, out, smask, t);
  }
  for (int tc = 0; tc < 8; ++tc) {
    k5_bpri<<<1024, 256, 0, stream>>>(out + OUT_B, wbpri_b, bbpri, hpri, tc);
    k6_spri<<<256, 256, 0, stream>>>(hpri, wspri_b, bspri, npri, out, tc);
  }
}